// Round 1
// baseline (542.871 us; speedup 1.0000x reference)
//
#include <hip/hip_runtime.h>

// Shapes: B=4, S=2048, D=256, H=8, KD=256; N=B*S=8192; H*KD=2048.
using bf16x8 = __attribute__((ext_vector_type(8))) __bf16;
using f32x4  = __attribute__((ext_vector_type(4))) float;
typedef unsigned short u16;
typedef const __attribute__((address_space(1))) void* gas_p;
typedef __attribute__((address_space(3))) void* las_p;

__device__ __forceinline__ u16 f2bf(float f) {
  union { float f; unsigned u; } v; v.f = f;
  unsigned r = v.u + 0x7fffu + ((v.u >> 16) & 1u);
  return (u16)(r >> 16);
}

__device__ __forceinline__ void gload16(const void* g, void* l) {
  __builtin_amdgcn_global_load_lds((gas_p)g, (las_p)l, 16, 0, 0);
}

#define MFMA(a, b, c) __builtin_amdgcn_mfma_f32_16x16x32_bf16((a), (b), (c), 0, 0, 0)

// ---------------------------------------------------------------------------
// Kernel 1: transpose + f32->bf16 convert for the 4 weight matrices.
// z=0..2: Wq/Wk/Wv [256][2048] -> [2048][256] bf16 (B^T layout for proj GEMM)
// z=3:    Wo [2048][256] -> [256][2048] bf16 (B^T layout for out GEMM)
__global__ __launch_bounds__(256) void transpose_conv(
    const float* __restrict__ Wq, const float* __restrict__ Wk,
    const float* __restrict__ Wv, const float* __restrict__ Wo,
    u16* __restrict__ wqt, u16* __restrict__ wkt,
    u16* __restrict__ wvt, u16* __restrict__ wot)
{
  int z = blockIdx.y;
  const float* src = (z == 0) ? Wq : (z == 1) ? Wk : (z == 2) ? Wv : Wo;
  u16* dst = (z == 0) ? wqt : (z == 1) ? wkt : (z == 2) ? wvt : wot;
  int C = (z < 3) ? 2048 : 256;   // src cols
  int R = (z < 3) ? 256 : 2048;   // src rows
  int TC = C >> 5;
  int tc = blockIdx.x % TC, tr = blockIdx.x / TC;
  __shared__ float tile[32][33];
  int j = threadIdx.x & 31, i0 = threadIdx.x >> 5;
#pragma unroll
  for (int p = 0; p < 4; p++)
    tile[i0 + p * 8][j] = src[(tr * 32 + i0 + p * 8) * C + tc * 32 + j];
  __syncthreads();
#pragma unroll
  for (int p = 0; p < 4; p++)
    dst[(tc * 32 + i0 + p * 8) * R + tr * 32 + j] = f2bf(tile[j][i0 + p * 8]);
}

// ---------------------------------------------------------------------------
// Kernel 2: LayerNorm for the 3 input streams, f32 -> bf16. One wave per row.
__global__ __launch_bounds__(256) void ln3_kernel(
    const float* __restrict__ xq, const float* __restrict__ xk, const float* __restrict__ xv,
    const float* __restrict__ gq, const float* __restrict__ bq,
    const float* __restrict__ gk, const float* __restrict__ bk,
    const float* __restrict__ gv, const float* __restrict__ bv,
    u16* __restrict__ oq, u16* __restrict__ ok, u16* __restrict__ ov)
{
  int z = blockIdx.y;
  const float* x = (z == 0) ? xq : (z == 1) ? xk : xv;
  const float* g = (z == 0) ? gq : (z == 1) ? gk : gv;
  const float* be = (z == 0) ? bq : (z == 1) ? bk : bv;
  u16* o = (z == 0) ? oq : (z == 1) ? ok : ov;
  int w = threadIdx.x >> 6, l = threadIdx.x & 63;
  int row = blockIdx.x * 4 + w;
  float4 x4 = *(const float4*)(x + row * 256 + l * 4);
  float s = x4.x + x4.y + x4.z + x4.w;
  float sq = x4.x * x4.x + x4.y * x4.y + x4.z * x4.z + x4.w * x4.w;
#pragma unroll
  for (int mm = 1; mm < 64; mm <<= 1) { s += __shfl_xor(s, mm); sq += __shfl_xor(sq, mm); }
  float mu = s * (1.f / 256.f);
  float var = sq * (1.f / 256.f) - mu * mu;
  float rs = rsqrtf(var + 1e-5f);
  float4 g4 = *(const float4*)(g + l * 4);
  float4 b4 = *(const float4*)(be + l * 4);
  ushort4 o4;
  o4.x = f2bf((x4.x - mu) * rs * g4.x + b4.x);
  o4.y = f2bf((x4.y - mu) * rs * g4.y + b4.y);
  o4.z = f2bf((x4.z - mu) * rs * g4.z + b4.z);
  o4.w = f2bf((x4.w - mu) * rs * g4.w + b4.w);
  *(ushort4*)(o + row * 256 + l * 4) = o4;
}

// ---------------------------------------------------------------------------
// Kernel 3: projection GEMM. C[8192][2048] = A[8192][256] * W[256][2048] (+bias)
// A, B^T both [rows][256] bf16. 128x128 tile, BK=64, 4 waves (2x2), 16x16x32 MFMA.
// Epilogue scatters to [B(4),H(8),S(2048),KD(256)]; q stream scaled by 1/16.
__global__ __launch_bounds__(256) void proj_gemm(
    const u16* __restrict__ qn, const u16* __restrict__ kn, const u16* __restrict__ vn,
    const u16* __restrict__ wqt, const u16* __restrict__ wkt, const u16* __restrict__ wvt,
    const float* __restrict__ bq, const float* __restrict__ bk, const float* __restrict__ bv,
    u16* __restrict__ qo, u16* __restrict__ ko, u16* __restrict__ vo)
{
  __shared__ u16 As[128 * 64];
  __shared__ u16 Bs[128 * 64];
  int z = blockIdx.z;
  const u16* A  = (z == 0) ? qn : (z == 1) ? kn : vn;
  const u16* Bt = (z == 0) ? wqt : (z == 1) ? wkt : wvt;
  const float* bias = (z == 0) ? bq : (z == 1) ? bk : bv;
  u16* Co = (z == 0) ? qo : (z == 1) ? ko : vo;
  float scale = (z == 0) ? 0.0625f : 1.0f;

  int i0 = blockIdx.x * 128, n0 = blockIdx.y * 128;
  int tid = threadIdx.x, w = tid >> 6, l = tid & 63;
  int wr = w >> 1, wc = w & 1, l15 = l & 15, qv = l >> 4;

  f32x4 acc[4][4] = {};

  for (int k0 = 0; k0 < 256; k0 += 64) {
    __syncthreads();
#pragma unroll
    for (int j = 0; j < 4; j++) {
      int c = (w * 4 + j) * 64 + l;
      int row = c >> 3, co = (c & 7) * 8;
      gload16(A + (i0 + row) * 256 + k0 + co, (char*)As + (w * 4 + j) * 1024);
      gload16(Bt + (n0 + row) * 256 + k0 + co, (char*)Bs + (w * 4 + j) * 1024);
    }
    __syncthreads();
#pragma unroll
    for (int kk = 0; kk < 2; kk++) {
      bf16x8 a[4], bfr[4];
#pragma unroll
      for (int m = 0; m < 4; m++)
        a[m] = *(const bf16x8*)(As + (wr * 64 + m * 16 + l15) * 64 + kk * 32 + qv * 8);
#pragma unroll
      for (int n = 0; n < 4; n++)
        bfr[n] = *(const bf16x8*)(Bs + (wc * 64 + n * 16 + l15) * 64 + kk * 32 + qv * 8);
#pragma unroll
      for (int m = 0; m < 4; m++)
#pragma unroll
        for (int n = 0; n < 4; n++) acc[m][n] = MFMA(a[m], bfr[n], acc[m][n]);
    }
  }

#pragma unroll
  for (int n = 0; n < 4; n++) {
    int col = n0 + wc * 64 + n * 16 + l15;
    float bc = bias[col];
    int h = col >> 8, kd = col & 255;
#pragma unroll
    for (int m = 0; m < 4; m++) {
#pragma unroll
      for (int r = 0; r < 4; r++) {
        int row = i0 + wr * 64 + m * 16 + qv * 4 + r;
        int bb = row >> 11, ss = row & 2047;
        Co[((bb * 8 + h) * 2048 + ss) * 256 + kd] = f2bf((acc[m][n][r] + bc) * scale);
      }
    }
  }
}

// ---------------------------------------------------------------------------
// Kernel 4: per-(b,h) transpose of V: [2048][256] -> [256][2048] bf16.
__global__ __launch_bounds__(256) void transpose_v_kernel(
    const u16* __restrict__ v, u16* __restrict__ vt)
{
  int bh = blockIdx.y;
  int tc = blockIdx.x & 7, tr = blockIdx.x >> 3;
  const u16* src = v + bh * 2048 * 256;
  u16* dst = vt + bh * 2048 * 256;
  __shared__ u16 tile[32][34];
  int j2 = threadIdx.x & 15, i0 = threadIdx.x >> 4;
#pragma unroll
  for (int p = 0; p < 2; p++) {
    int i = i0 + p * 16;
    unsigned u = *(const unsigned*)(src + (tr * 32 + i) * 256 + tc * 32 + j2 * 2);
    tile[i][j2 * 2] = (u16)u; tile[i][j2 * 2 + 1] = (u16)(u >> 16);
  }
  __syncthreads();
#pragma unroll
  for (int p = 0; p < 2; p++) {
    int i = i0 + p * 16;
    unsigned u = (unsigned)tile[j2 * 2][i] | ((unsigned)tile[j2 * 2 + 1][i] << 16);
    *(unsigned*)(dst + (tc * 32 + i) * 2048 + tr * 32 + j2 * 2) = u;
  }
}

// ---------------------------------------------------------------------------
// Kernel 5: flash attention. grid (32 q-tiles, 32 bh). 4 waves x 16 q-rows.
// Q pre-scaled bf16 [32][2048][256]; K [32][2048][256]; Vt [32][256][2048].
// K/V staged with XOR swizzle (byte ^= (row&7)<<4) via pre-permuted global src.
__global__ __launch_bounds__(256) void flash_attn(
    const u16* __restrict__ q, const u16* __restrict__ k,
    const u16* __restrict__ vt, u16* __restrict__ o)
{
  __shared__ u16 Ks[64 * 256];   // [64 s][512B phys] swizzled
  __shared__ u16 Vs[256 * 64];   // [256 d][128B phys] swizzled
  __shared__ u16 Ps[4][16 * 64]; // per-wave [16 q][128B phys] swizzled
  int qt = blockIdx.x, bh = blockIdx.y;
  int b = bh >> 3, h = bh & 7;
  int tid = threadIdx.x, w = tid >> 6, l = tid & 63;
  int l15 = l & 15, qv = l >> 4;

  const u16* Q = q + (bh * 2048 + qt * 64 + w * 16) * 256;
  const u16* K = k + bh * 2048 * 256;
  const u16* V = vt + bh * 256 * 2048;

  bf16x8 qf[8];
#pragma unroll
  for (int kk = 0; kk < 8; kk++)
    qf[kk] = *(const bf16x8*)(Q + l15 * 256 + kk * 32 + qv * 8);

  f32x4 oacc[16] = {};
  float mrun[4] = {-1e30f, -1e30f, -1e30f, -1e30f};
  float lrun[4] = {0.f, 0.f, 0.f, 0.f};
  u16* pb = &Ps[w][0];

  for (int t = 0; t < 32; t++) {
    int kv0 = t * 64;
    __syncthreads();
#pragma unroll
    for (int j = 0; j < 8; j++) {
      int c = (w * 8 + j) * 64 + l;
      int kr = c >> 5, ksl = c & 31;
      gload16(K + (kv0 + kr) * 256 + (ksl ^ (kr & 7)) * 8, (char*)Ks + (w * 8 + j) * 1024);
      int vr = c >> 3, vsl = c & 7;
      gload16(V + vr * 2048 + kv0 + (vsl ^ (vr & 7)) * 8, (char*)Vs + (w * 8 + j) * 1024);
    }
    __syncthreads();

    // QK^T: P[q(16)][s(64)] per wave.
    f32x4 p[4];
#pragma unroll
    for (int n = 0; n < 4; n++) {
      f32x4 acc = {0.f, 0.f, 0.f, 0.f};
      int krow = n * 16 + l15;
      const char* kb = (const char*)Ks + krow * 512;
      int swz = (krow & 7) << 4;
#pragma unroll
      for (int kk = 0; kk < 8; kk++) {
        bf16x8 bfr = *(const bf16x8*)(kb + ((kk * 64 + qv * 16) ^ swz));
        acc = MFMA(qf[kk], bfr, acc);
      }
      p[n] = acc;
    }

    // Online softmax with defer-max (THR=8). Rows q=(qv*4+r), cols at l15.
#pragma unroll
    for (int r = 0; r < 4; r++) {
      float mt = fmaxf(fmaxf(p[0][r], p[1][r]), fmaxf(p[2][r], p[3][r]));
#pragma unroll
      for (int mm = 1; mm < 16; mm <<= 1) mt = fmaxf(mt, __shfl_xor(mt, mm));
      if (mt > mrun[r] + 8.0f) {
        float f = __expf(mrun[r] - mt);
        lrun[r] *= f;
        mrun[r] = mt;
#pragma unroll
        for (int d = 0; d < 16; d++) oacc[d][r] *= f;
      }
      float s = 0.f;
#pragma unroll
      for (int n = 0; n < 4; n++) {
        float e = __expf(p[n][r] - mrun[r]);
        p[n][r] = e;
        s += e;
      }
#pragma unroll
      for (int mm = 1; mm < 16; mm <<= 1) s += __shfl_xor(s, mm);
      lrun[r] += s;
    }

    // P -> per-wave LDS (bf16, swizzled); same-wave DS ops are in-order.
#pragma unroll
    for (int n = 0; n < 4; n++) {
#pragma unroll
      for (int r = 0; r < 4; r++) {
        int qq = qv * 4 + r;
        int cb = (n * 16 + l15) * 2;
        *(u16*)((char*)pb + qq * 128 + (cb ^ ((qq & 7) << 4))) = f2bf(p[n][r]);
      }
    }

    // PV: O[q][d] += P[q][s] * V[s][d], V read from transposed swizzled tile.
#pragma unroll
    for (int ks2 = 0; ks2 < 2; ks2++) {
      bf16x8 af = *(const bf16x8*)((const char*)pb + l15 * 128 +
                                   ((ks2 * 64 + qv * 16) ^ ((l15 & 7) << 4)));
#pragma unroll
      for (int d = 0; d < 16; d++) {
        int vrow = d * 16 + l15;
        bf16x8 bfr = *(const bf16x8*)((const char*)Vs + vrow * 128 +
                                      ((ks2 * 64 + qv * 16) ^ ((vrow & 7) << 4)));
        oacc[d] = MFMA(af, bfr, oacc[d]);
      }
    }
  }

  // Epilogue: normalize and write attn to [8192][2048] at col h*256+d.
  int orow0 = b * 2048 + qt * 64 + w * 16;
#pragma unroll
  for (int r = 0; r < 4; r++) {
    float inv = 1.0f / lrun[r];
    int rowbase = (orow0 + qv * 4 + r) * 2048 + h * 256;
#pragma unroll
    for (int d = 0; d < 16; d++)
      o[rowbase + d * 16 + l15] = f2bf(oacc[d][r] * inv);
  }
}

// ---------------------------------------------------------------------------
// Kernel 6: output projection + bias + residual.
// out[8192][256] = attn[8192][2048] * Wo[2048][256] + bo + input_query. f32 out.
// BM=128, BN=64, BK=64, 4 waves (4x1), each wave 32x64.
__global__ __launch_bounds__(256) void out_gemm(
    const u16* __restrict__ A, const u16* __restrict__ Bt,
    const float* __restrict__ bo, const float* __restrict__ resid,
    float* __restrict__ out)
{
  __shared__ u16 As[128 * 64];
  __shared__ u16 Bs[64 * 64];
  int i0 = blockIdx.x * 128, n0 = blockIdx.y * 64;
  int tid = threadIdx.x, w = tid >> 6, l = tid & 63, l15 = l & 15, qv = l >> 4;

  f32x4 acc[2][4] = {};

  for (int k0 = 0; k0 < 2048; k0 += 64) {
    __syncthreads();
#pragma unroll
    for (int j = 0; j < 4; j++) {
      int c = (w * 4 + j) * 64 + l;
      int row = c >> 3, co = (c & 7) * 8;
      gload16(A + (i0 + row) * 2048 + k0 + co, (char*)As + (w * 4 + j) * 1024);
    }
#pragma unroll
    for (int j = 0; j < 2; j++) {
      int c = (w * 2 + j) * 64 + l;
      int row = c >> 3, co = (c & 7) * 8;
      gload16(Bt + (n0 + row) * 2048 + k0 + co, (char*)Bs + (w * 2 + j) * 1024);
    }
    __syncthreads();
#pragma unroll
    for (int kk = 0; kk < 2; kk++) {
      bf16x8 a[2], bfr[4];
#pragma unroll
      for (int m = 0; m < 2; m++)
        a[m] = *(const bf16x8*)(As + (w * 32 + m * 16 + l15) * 64 + kk * 32 + qv * 8);
#pragma unroll
      for (int n = 0; n < 4; n++)
        bfr[n] = *(const bf16x8*)(Bs + (n * 16 + l15) * 64 + kk * 32 + qv * 8);
#pragma unroll
      for (int m = 0; m < 2; m++)
#pragma unroll
        for (int n = 0; n < 4; n++) acc[m][n] = MFMA(a[m], bfr[n], acc[m][n]);
    }
  }

#pragma unroll
  for (int n = 0; n < 4; n++) {
    int col = n0 + n * 16 + l15;
    float bc = bo[col];
#pragma unroll
    for (int m = 0; m < 2; m++)
#pragma unroll
      for (int r = 0; r < 4; r++) {
        int row = i0 + w * 32 + m * 16 + qv * 4 + r;
        out[row * 256 + col] = acc[m][n][r] + bc + resid[row * 256 + col];
      }
  }
}

// ---------------------------------------------------------------------------
extern "C" void kernel_launch(void* const* d_in, const int* in_sizes, int n_in,
                              void* d_out, int out_size, void* d_ws, size_t ws_size,
                              hipStream_t stream)
{
  const float* inq  = (const float*)d_in[0];
  const float* key  = (const float*)d_in[1];
  const float* val  = (const float*)d_in[2];
  const float* gq   = (const float*)d_in[3];
  const float* bqln = (const float*)d_in[4];
  const float* gk   = (const float*)d_in[5];
  const float* bkln = (const float*)d_in[6];
  const float* gv   = (const float*)d_in[7];
  const float* bvln = (const float*)d_in[8];
  const float* Wq   = (const float*)d_in[9];
  const float* bq   = (const float*)d_in[10];
  const float* Wk   = (const float*)d_in[11];
  const float* bk   = (const float*)d_in[12];
  const float* Wv   = (const float*)d_in[13];
  const float* bv   = (const float*)d_in[14];
  const float* Wo   = (const float*)d_in[15];
  const float* bo   = (const float*)d_in[16];

  char* ws = (char*)d_ws;
  const size_t MB = 1ull << 20;
  u16* wqt = (u16*)(ws + 0 * MB);    // [2048][256] bf16
  u16* wkt = (u16*)(ws + 1 * MB);
  u16* wvt = (u16*)(ws + 2 * MB);
  u16* wot = (u16*)(ws + 3 * MB);    // [256][2048] bf16
  u16* qn  = (u16*)(ws + 4 * MB);    // [8192][256] bf16
  u16* kn  = (u16*)(ws + 8 * MB);
  u16* vn  = (u16*)(ws + 12 * MB);
  u16* qws = (u16*)(ws + 16 * MB);   // [32][2048][256] bf16 (q, pre-scaled)
  u16* kws = (u16*)(ws + 48 * MB);   // [32][2048][256] bf16
  u16* vws = (u16*)(ws + 80 * MB);   // [32][2048][256] bf16 (row-major V, temp)
  u16* vtw = (u16*)(ws + 112 * MB);  // [32][256][2048] bf16 (V^T)
  u16* attn = vws;                   // reuse: V row-major dead after transpose

  transpose_conv<<<dim3(512, 4), 256, 0, stream>>>(Wq, Wk, Wv, Wo, wqt, wkt, wvt, wot);
  ln3_kernel<<<dim3(2048, 3), 256, 0, stream>>>(inq, key, val, gq, bqln, gk, bkln, gv, bvln,
                                                qn, kn, vn);
  proj_gemm<<<dim3(64, 16, 3), 256, 0, stream>>>(qn, kn, vn, wqt, wkt, wvt, bq, bk, bv,
                                                 qws, kws, vws);
  transpose_v_kernel<<<dim3(512, 32), 256, 0, stream>>>(vws, vtw);
  flash_attn<<<dim3(32, 32), 256, 0, stream>>>(qws, kws, vtw, attn);
  out_gemm<<<dim3(64, 4), 256, 0, stream>>>(attn, wot, bo, inq, (float*)d_out);
}

// Round 2
// 298.578 us; speedup vs baseline: 1.8182x; 1.8182x over previous
//
#include <hip/hip_runtime.h>

// Shapes: B=4, S=2048, D=256, H=8, KD=256; N=B*S=8192; H*KD=2048.
using bf16x8 = __attribute__((ext_vector_type(8))) __bf16;
using f32x4  = __attribute__((ext_vector_type(4))) float;
using f32x16 = __attribute__((ext_vector_type(16))) float;
typedef unsigned short u16;
typedef const __attribute__((address_space(1))) void* gas_p;
typedef __attribute__((address_space(3))) void* las_p;

__device__ __forceinline__ u16 f2bf(float f) {
  union { float f; unsigned u; } v; v.f = f;
  unsigned r = v.u + 0x7fffu + ((v.u >> 16) & 1u);
  return (u16)(r >> 16);
}

__device__ __forceinline__ unsigned pkbf(float a, float b) {
  unsigned r;
  asm("v_cvt_pk_bf16_f32 %0, %1, %2" : "=v"(r) : "v"(a), "v"(b));
  return r;
}

__device__ __forceinline__ void gload16(const void* g, void* l) {
  __builtin_amdgcn_global_load_lds((gas_p)g, (las_p)l, 16, 0, 0);
}

#define MFMA(a, b, c)   __builtin_amdgcn_mfma_f32_16x16x32_bf16((a), (b), (c), 0, 0, 0)
#define MFMA32(a, b, c) __builtin_amdgcn_mfma_f32_32x32x16_bf16((a), (b), (c), 0, 0, 0)

// ---------------------------------------------------------------------------
// Kernel 1: transpose + f32->bf16 convert for the 4 weight matrices.
__global__ __launch_bounds__(256) void transpose_conv(
    const float* __restrict__ Wq, const float* __restrict__ Wk,
    const float* __restrict__ Wv, const float* __restrict__ Wo,
    u16* __restrict__ wqt, u16* __restrict__ wkt,
    u16* __restrict__ wvt, u16* __restrict__ wot)
{
  int z = blockIdx.y;
  const float* src = (z == 0) ? Wq : (z == 1) ? Wk : (z == 2) ? Wv : Wo;
  u16* dst = (z == 0) ? wqt : (z == 1) ? wkt : (z == 2) ? wvt : wot;
  int C = (z < 3) ? 2048 : 256;   // src cols
  int R = (z < 3) ? 256 : 2048;   // src rows
  int TC = C >> 5;
  int tc = blockIdx.x % TC, tr = blockIdx.x / TC;
  __shared__ float tile[32][33];
  int j = threadIdx.x & 31, i0 = threadIdx.x >> 5;
#pragma unroll
  for (int p = 0; p < 4; p++)
    tile[i0 + p * 8][j] = src[(tr * 32 + i0 + p * 8) * C + tc * 32 + j];
  __syncthreads();
#pragma unroll
  for (int p = 0; p < 4; p++)
    dst[(tc * 32 + i0 + p * 8) * R + tr * 32 + j] = f2bf(tile[j][i0 + p * 8]);
}

// ---------------------------------------------------------------------------
// Kernel 2: LayerNorm for the 3 input streams, f32 -> bf16. One wave per row.
__global__ __launch_bounds__(256) void ln3_kernel(
    const float* __restrict__ xq, const float* __restrict__ xk, const float* __restrict__ xv,
    const float* __restrict__ gq, const float* __restrict__ bq,
    const float* __restrict__ gk, const float* __restrict__ bk,
    const float* __restrict__ gv, const float* __restrict__ bv,
    u16* __restrict__ oq, u16* __restrict__ ok, u16* __restrict__ ov)
{
  int z = blockIdx.y;
  const float* x = (z == 0) ? xq : (z == 1) ? xk : xv;
  const float* g = (z == 0) ? gq : (z == 1) ? gk : gv;
  const float* be = (z == 0) ? bq : (z == 1) ? bk : bv;
  u16* o = (z == 0) ? oq : (z == 1) ? ok : ov;
  int w = threadIdx.x >> 6, l = threadIdx.x & 63;
  int row = blockIdx.x * 4 + w;
  float4 x4 = *(const float4*)(x + row * 256 + l * 4);
  float s = x4.x + x4.y + x4.z + x4.w;
  float sq = x4.x * x4.x + x4.y * x4.y + x4.z * x4.z + x4.w * x4.w;
#pragma unroll
  for (int mm = 1; mm < 64; mm <<= 1) { s += __shfl_xor(s, mm); sq += __shfl_xor(sq, mm); }
  float mu = s * (1.f / 256.f);
  float var = sq * (1.f / 256.f) - mu * mu;
  float rs = rsqrtf(var + 1e-5f);
  float4 g4 = *(const float4*)(g + l * 4);
  float4 b4 = *(const float4*)(be + l * 4);
  ushort4 o4;
  o4.x = f2bf((x4.x - mu) * rs * g4.x + b4.x);
  o4.y = f2bf((x4.y - mu) * rs * g4.y + b4.y);
  o4.z = f2bf((x4.z - mu) * rs * g4.z + b4.z);
  o4.w = f2bf((x4.w - mu) * rs * g4.w + b4.w);
  *(ushort4*)(o + row * 256 + l * 4) = o4;
}

// ---------------------------------------------------------------------------
// Kernel 3: projection GEMM. C[8192][2048] = A[8192][256] * W[256][2048] (+bias)
__global__ __launch_bounds__(256) void proj_gemm(
    const u16* __restrict__ qn, const u16* __restrict__ kn, const u16* __restrict__ vn,
    const u16* __restrict__ wqt, const u16* __restrict__ wkt, const u16* __restrict__ wvt,
    const float* __restrict__ bq, const float* __restrict__ bk, const float* __restrict__ bv,
    u16* __restrict__ qo, u16* __restrict__ ko, u16* __restrict__ vo)
{
  __shared__ u16 As[128 * 64];
  __shared__ u16 Bs[128 * 64];
  int z = blockIdx.z;
  const u16* A  = (z == 0) ? qn : (z == 1) ? kn : vn;
  const u16* Bt = (z == 0) ? wqt : (z == 1) ? wkt : wvt;
  const float* bias = (z == 0) ? bq : (z == 1) ? bk : bv;
  u16* Co = (z == 0) ? qo : (z == 1) ? ko : vo;
  float scale = (z == 0) ? 0.0625f : 1.0f;

  int i0 = blockIdx.x * 128, n0 = blockIdx.y * 128;
  int tid = threadIdx.x, w = tid >> 6, l = tid & 63;
  int wr = w >> 1, wc = w & 1, l15 = l & 15, qv = l >> 4;

  f32x4 acc[4][4] = {};

  for (int k0 = 0; k0 < 256; k0 += 64) {
    __syncthreads();
#pragma unroll
    for (int j = 0; j < 4; j++) {
      int c = (w * 4 + j) * 64 + l;
      int row = c >> 3, co = (c & 7) * 8;
      gload16(A + (i0 + row) * 256 + k0 + co, (char*)As + (w * 4 + j) * 1024);
      gload16(Bt + (n0 + row) * 256 + k0 + co, (char*)Bs + (w * 4 + j) * 1024);
    }
    __syncthreads();
#pragma unroll
    for (int kk = 0; kk < 2; kk++) {
      bf16x8 a[4], bfr[4];
#pragma unroll
      for (int m = 0; m < 4; m++)
        a[m] = *(const bf16x8*)(As + (wr * 64 + m * 16 + l15) * 64 + kk * 32 + qv * 8);
#pragma unroll
      for (int n = 0; n < 4; n++)
        bfr[n] = *(const bf16x8*)(Bs + (wc * 64 + n * 16 + l15) * 64 + kk * 32 + qv * 8);
#pragma unroll
      for (int m = 0; m < 4; m++)
#pragma unroll
        for (int n = 0; n < 4; n++) acc[m][n] = MFMA(a[m], bfr[n], acc[m][n]);
    }
  }

#pragma unroll
  for (int n = 0; n < 4; n++) {
    int col = n0 + wc * 64 + n * 16 + l15;
    float bc = bias[col];
    int h = col >> 8, kd = col & 255;
#pragma unroll
    for (int m = 0; m < 4; m++) {
#pragma unroll
      for (int r = 0; r < 4; r++) {
        int row = i0 + wr * 64 + m * 16 + qv * 4 + r;
        int bb = row >> 11, ss = row & 2047;
        Co[((bb * 8 + h) * 2048 + ss) * 256 + kd] = f2bf((acc[m][n][r] + bc) * scale);
      }
    }
  }
}

// ---------------------------------------------------------------------------
// Kernel 4: per-(b,h) transpose of V: [2048][256] -> [256][2048] bf16.
__global__ __launch_bounds__(256) void transpose_v_kernel(
    const u16* __restrict__ v, u16* __restrict__ vt)
{
  int bh = blockIdx.y;
  int tc = blockIdx.x & 7, tr = blockIdx.x >> 3;
  const u16* src = v + bh * 2048 * 256;
  u16* dst = vt + bh * 2048 * 256;
  __shared__ u16 tile[32][34];
  int j2 = threadIdx.x & 15, i0 = threadIdx.x >> 4;
#pragma unroll
  for (int p = 0; p < 2; p++) {
    int i = i0 + p * 16;
    unsigned u = *(const unsigned*)(src + (tr * 32 + i) * 256 + tc * 32 + j2 * 2);
    tile[i][j2 * 2] = (u16)u; tile[i][j2 * 2 + 1] = (u16)(u >> 16);
  }
  __syncthreads();
#pragma unroll
  for (int p = 0; p < 2; p++) {
    int i = i0 + p * 16;
    unsigned u = (unsigned)tile[j2 * 2][i] | ((unsigned)tile[j2 * 2 + 1][i] << 16);
    *(unsigned*)(dst + (tc * 32 + i) * 2048 + tr * 32 + j2 * 2) = u;
  }
}

// ---------------------------------------------------------------------------
// Kernel 5: flash attention, 32x32x16 MFMA, swapped operands (in-reg softmax).
// 8 waves x 32 q-rows = 256 q/block; grid (8 qt, 32 bh) = 256 blocks (1/CU).
// K tile [64][256] bf16, rows 512B, 5-bit XOR swizzle (conflict-free).
// V^T tile packed as [128 rows][256B] (two d per row), 4-bit XOR swizzle.
// QK^T: S^T = mfma(K, Q) -> lane owns q = lane&31, s lane-local.
// PV:   O^T = mfma(V^T, P^T) -> lane keeps q = lane&31 (rescale lane-local).
__global__ __launch_bounds__(512, 2) void flash_attn(
    const u16* __restrict__ q, const u16* __restrict__ k,
    const u16* __restrict__ vt, u16* __restrict__ o)
{
  __shared__ char lds[65536];   // [0,32K): K tile; [32K,64K): V^T tile
  int qt = blockIdx.x, bh = blockIdx.y;
  int b = bh >> 3, hh = bh & 7;
  int tid = threadIdx.x, w = tid >> 6, l = tid & 63;
  int l31 = l & 31, h = l >> 5;

  const u16* Q = q + (size_t)(bh * 2048 + qt * 256 + w * 32) * 256;
  const u16* K = k + (size_t)bh * 2048 * 256;
  const u16* V = vt + (size_t)bh * 256 * 2048;   // V^T [256][2048]

  // Q B-fragments: lane holds q-row = l31, d-slice = dt*16 + h*8 .. +8.
  bf16x8 qf[16];
#pragma unroll
  for (int dt = 0; dt < 16; dt++)
    qf[dt] = *(const bf16x8*)(Q + l31 * 256 + dt * 16 + h * 8);

  f32x16 oacc[8] = {};
  float m_ = -1e30f, lsum = 0.f;

  for (int t = 0; t < 32; t++) {
    __syncthreads();
#pragma unroll
    for (int j = 0; j < 4; j++) {
      int c = w * 4 + j;
      int off = c * 1024 + l * 16;
      {
        int r = off >> 9, ps = l & 31;                 // K: row r, phys slot ps
        gload16(K + (size_t)(t * 64 + r) * 256 + ((ps ^ (r & 31)) << 3),
                (char*)lds + off);
      }
      {
        int r = off >> 8, ps = l & 15;                 // V: 256B row r
        int lsl = ps ^ (r & 15);
        int d = r * 2 + (lsl >> 3);
        gload16(V + (size_t)d * 2048 + t * 64 + ((lsl & 7) << 3),
                (char*)lds + 32768 + off);
      }
    }
    __syncthreads();

    // ---- QK^T: p0 = s-tile [0,32), p1 = s-tile [32,64); lane col q = l31.
    f32x16 p0 = {}, p1 = {};
#pragma unroll
    for (int dt = 0; dt < 16; dt++) {
      int sl = ((dt * 2 + h) ^ l31) << 4;
      bf16x8 kf0 = *(const bf16x8*)((char*)lds + l31 * 512 + sl);
      bf16x8 kf1 = *(const bf16x8*)((char*)lds + (32 + l31) * 512 + sl);
      p0 = MFMA32(kf0, qf[dt], p0);
      p1 = MFMA32(kf1, qf[dt], p1);
    }

    // ---- online softmax (lane-local; q = l31 on both halves).
    float n0 = fmaxf(fmaxf(p0[0], p0[1]), fmaxf(p0[2], p0[3]));
    float n1 = fmaxf(fmaxf(p0[4], p0[5]), fmaxf(p0[6], p0[7]));
    float n2 = fmaxf(fmaxf(p0[8], p0[9]), fmaxf(p0[10], p0[11]));
    float n3 = fmaxf(fmaxf(p0[12], p0[13]), fmaxf(p0[14], p0[15]));
    float n4 = fmaxf(fmaxf(p1[0], p1[1]), fmaxf(p1[2], p1[3]));
    float n5 = fmaxf(fmaxf(p1[4], p1[5]), fmaxf(p1[6], p1[7]));
    float n6 = fmaxf(fmaxf(p1[8], p1[9]), fmaxf(p1[10], p1[11]));
    float n7 = fmaxf(fmaxf(p1[12], p1[13]), fmaxf(p1[14], p1[15]));
    float mt = fmaxf(fmaxf(fmaxf(n0, n1), fmaxf(n2, n3)),
                     fmaxf(fmaxf(n4, n5), fmaxf(n6, n7)));
    mt = fmaxf(mt, __shfl_xor(mt, 32));
    if (__any(mt > m_ + 8.0f)) {               // defer-max (T13)
      float mn = fmaxf(m_, mt);
      float f = __expf(m_ - mn);
      lsum *= f;
#pragma unroll
      for (int dt = 0; dt < 8; dt++)
#pragma unroll
        for (int i = 0; i < 16; i++) oacc[dt][i] *= f;
      m_ = mn;
    }
#pragma unroll
    for (int i = 0; i < 16; i++) { p0[i] = __expf(p0[i] - m_); lsum += p0[i]; }
#pragma unroll
    for (int i = 0; i < 16; i++) { p1[i] = __expf(p1[i] - m_); lsum += p1[i]; }

    // ---- pack P to bf16 pairs (ascending s within each half).
    unsigned pw[16];
#pragma unroll
    for (int i = 0; i < 8; i++) pw[i] = pkbf(p0[2 * i], p0[2 * i + 1]);
#pragma unroll
    for (int i = 0; i < 8; i++) pw[8 + i] = pkbf(p1[2 * i], p1[2 * i + 1]);

    // ---- PV: per k-tile build P^T B-frag (cross-half exchange), 8 d-tiles.
#pragma unroll
    for (int kt = 0; kt < 4; kt++) {
      unsigned x0 = __shfl_xor(pw[4 * kt + 0], 32);
      unsigned x1 = __shfl_xor(pw[4 * kt + 1], 32);
      unsigned x2 = __shfl_xor(pw[4 * kt + 2], 32);
      unsigned x3 = __shfl_xor(pw[4 * kt + 3], 32);
      union { unsigned u[4]; bf16x8 v; } pa;
      pa.u[0] = h ? x2 : pw[4 * kt + 0];
      pa.u[1] = h ? x3 : pw[4 * kt + 1];
      pa.u[2] = h ? pw[4 * kt + 2] : x0;
      pa.u[3] = h ? pw[4 * kt + 3] : x1;
#pragma unroll
      for (int dt = 0; dt < 8; dt++) {
        int d = dt * 32 + l31;
        int r = d >> 1;
        int lsl = (d & 1) * 8 + kt * 2 + h;
        bf16x8 vf = *(const bf16x8*)((char*)lds + 32768 + r * 256 +
                                     ((lsl ^ (r & 15)) << 4));
        oacc[dt] = MFMA32(vf, pa.v, oacc[dt]);
      }
    }
  }

  // ---- epilogue: normalize (lane-local q), transpose via LDS, store 16B.
  __syncthreads();
  float inv = 1.0f / (lsum + __shfl_xor(lsum, 32));
  char* wbase = (char*)lds + w * 8192;   // 16 q-rows x 512B per warp region
  int qr15 = l31 & 15;
#pragma unroll
  for (int ph = 0; ph < 2; ph++) {
    if ((l31 >> 4) == ph) {
#pragma unroll
      for (int dt = 0; dt < 8; dt++) {
#pragma unroll
        for (int rg = 0; rg < 4; rg++) {
          uint2 uu;
          uu.x = pkbf(oacc[dt][rg * 4 + 0] * inv, oacc[dt][rg * 4 + 1] * inv);
          uu.y = pkbf(oacc[dt][rg * 4 + 2] * inv, oacc[dt][rg * 4 + 3] * inv);
          *(uint2*)(wbase + qr15 * 512 + ((dt * 64 + rg * 16) ^ (qr15 << 4)) + h * 8) = uu;
        }
      }
    }
    asm volatile("s_waitcnt lgkmcnt(0)" ::: "memory");
    __builtin_amdgcn_sched_barrier(0);
#pragma unroll
    for (int c = 0; c < 8; c++) {
      int qr = c * 2 + h;
      uint4 vv = *(const uint4*)(wbase + qr * 512 + ((l31 ^ qr) << 4));
      int s = qt * 256 + w * 32 + ph * 16 + qr;
      *(uint4*)((char*)o + (size_t)(b * 2048 + s) * 4096 + hh * 512 + l31 * 16) = vv;
    }
    asm volatile("s_waitcnt lgkmcnt(0)" ::: "memory");
  }
}

// ---------------------------------------------------------------------------
// Kernel 6: output projection + bias + residual.
__global__ __launch_bounds__(256) void out_gemm(
    const u16* __restrict__ A, const u16* __restrict__ Bt,
    const float* __restrict__ bo, const float* __restrict__ resid,
    float* __restrict__ out)
{
  __shared__ u16 As[128 * 64];
  __shared__ u16 Bs[64 * 64];
  int i0 = blockIdx.x * 128, n0 = blockIdx.y * 64;
  int tid = threadIdx.x, w = tid >> 6, l = tid & 63, l15 = l & 15, qv = l >> 4;

  f32x4 acc[2][4] = {};

  for (int k0 = 0; k0 < 2048; k0 += 64) {
    __syncthreads();
#pragma unroll
    for (int j = 0; j < 4; j++) {
      int c = (w * 4 + j) * 64 + l;
      int row = c >> 3, co = (c & 7) * 8;
      gload16(A + (i0 + row) * 2048 + k0 + co, (char*)As + (w * 4 + j) * 1024);
    }
#pragma unroll
    for (int j = 0; j < 2; j++) {
      int c = (w * 2 + j) * 64 + l;
      int row = c >> 3, co = (c & 7) * 8;
      gload16(Bt + (n0 + row) * 2048 + k0 + co, (char*)Bs + (w * 2 + j) * 1024);
    }
    __syncthreads();
#pragma unroll
    for (int kk = 0; kk < 2; kk++) {
      bf16x8 a[2], bfr[4];
#pragma unroll
      for (int m = 0; m < 2; m++)
        a[m] = *(const bf16x8*)(As + (w * 32 + m * 16 + l15) * 64 + kk * 32 + qv * 8);
#pragma unroll
      for (int n = 0; n < 4; n++)
        bfr[n] = *(const bf16x8*)(Bs + (n * 16 + l15) * 64 + kk * 32 + qv * 8);
#pragma unroll
      for (int m = 0; m < 2; m++)
#pragma unroll
        for (int n = 0; n < 4; n++) acc[m][n] = MFMA(a[m], bfr[n], acc[m][n]);
    }
  }

#pragma unroll
  for (int n = 0; n < 4; n++) {
    int col = n0 + n * 16 + l15;
    float bc = bo[col];
#pragma unroll
    for (int m = 0; m < 2; m++)
#pragma unroll
      for (int r = 0; r < 4; r++) {
        int row = i0 + w * 32 + m * 16 + qv * 4 + r;
        out[row * 256 + col] = acc[m][n][r] + bc + resid[row * 256 + col];
      }
  }
}

// ---------------------------------------------------------------------------
extern "C" void kernel_launch(void* const* d_in, const int* in_sizes, int n_in,
                              void* d_out, int out_size, void* d_ws, size_t ws_size,
                              hipStream_t stream)
{
  const float* inq  = (const float*)d_in[0];
  const float* key  = (const float*)d_in[1];
  const float* val  = (const float*)d_in[2];
  const float* gq   = (const float*)d_in[3];
  const float* bqln = (const float*)d_in[4];
  const float* gk   = (const float*)d_in[5];
  const float* bkln = (const float*)d_in[6];
  const float* gv   = (const float*)d_in[7];
  const float* bvln = (const float*)d_in[8];
  const float* Wq   = (const float*)d_in[9];
  const float* bq   = (const float*)d_in[10];
  const float* Wk   = (const float*)d_in[11];
  const float* bk   = (const float*)d_in[12];
  const float* Wv   = (const float*)d_in[13];
  const float* bv   = (const float*)d_in[14];
  const float* Wo   = (const float*)d_in[15];
  const float* bo   = (const float*)d_in[16];

  char* ws = (char*)d_ws;
  const size_t MB = 1ull << 20;
  u16* wqt = (u16*)(ws + 0 * MB);    // [2048][256] bf16
  u16* wkt = (u16*)(ws + 1 * MB);
  u16* wvt = (u16*)(ws + 2 * MB);
  u16* wot = (u16*)(ws + 3 * MB);    // [256][2048] bf16
  u16* qn  = (u16*)(ws + 4 * MB);    // [8192][256] bf16
  u16* kn  = (u16*)(ws + 8 * MB);
  u16* vn  = (u16*)(ws + 12 * MB);
  u16* qws = (u16*)(ws + 16 * MB);   // [32][2048][256] bf16 (q, pre-scaled 1/16)
  u16* kws = (u16*)(ws + 48 * MB);   // [32][2048][256] bf16
  u16* vws = (u16*)(ws + 80 * MB);   // [32][2048][256] bf16 (row-major V, temp)
  u16* vtw = (u16*)(ws + 112 * MB);  // [32][256][2048] bf16 (V^T)
  u16* attn = vws;                   // reuse: V row-major dead after transpose

  transpose_conv<<<dim3(512, 4), 256, 0, stream>>>(Wq, Wk, Wv, Wo, wqt, wkt, wvt, wot);
  ln3_kernel<<<dim3(2048, 3), 256, 0, stream>>>(inq, key, val, gq, bqln, gk, bkln, gv, bvln,
                                                qn, kn, vn);
  proj_gemm<<<dim3(64, 16, 3), 256, 0, stream>>>(qn, kn, vn, wqt, wkt, wvt, bq, bk, bv,
                                                 qws, kws, vws);
  transpose_v_kernel<<<dim3(512, 32), 256, 0, stream>>>(vws, vtw);
  flash_attn<<<dim3(8, 32), 512, 0, stream>>>(qws, kws, vtw, attn);
  out_gemm<<<dim3(64, 4), 256, 0, stream>>>(attn, wot, bo, inq, (float*)d_out);
}

// Round 3
// 267.278 us; speedup vs baseline: 2.0311x; 1.1171x over previous
//
#include <hip/hip_runtime.h>

// Shapes: B=4, S=2048, D=256, H=8, KD=256; N=B*S=8192; H*KD=2048.
using bf16x8 = __attribute__((ext_vector_type(8))) __bf16;
using f32x4  = __attribute__((ext_vector_type(4))) float;
using f32x16 = __attribute__((ext_vector_type(16))) float;
typedef unsigned short u16;
typedef const __attribute__((address_space(1))) void* gas_p;
typedef __attribute__((address_space(3))) void* las_p;

__device__ __forceinline__ u16 f2bf(float f) {
  union { float f; unsigned u; } v; v.f = f;
  unsigned r = v.u + 0x7fffu + ((v.u >> 16) & 1u);
  return (u16)(r >> 16);
}

__device__ __forceinline__ unsigned pkbf(float a, float b) {
  unsigned r;
  asm("v_cvt_pk_bf16_f32 %0, %1, %2" : "=v"(r) : "v"(a), "v"(b));
  return r;
}

__device__ __forceinline__ void gload16(const void* g, void* l) {
  __builtin_amdgcn_global_load_lds((gas_p)g, (las_p)l, 16, 0, 0);
}

#define MFMA(a, b, c)   __builtin_amdgcn_mfma_f32_16x16x32_bf16((a), (b), (c), 0, 0, 0)
#define MFMA32(a, b, c) __builtin_amdgcn_mfma_f32_32x32x16_bf16((a), (b), (c), 0, 0, 0)

// ---------------------------------------------------------------------------
// Kernel 1: transpose + f32->bf16 convert for the 4 weight matrices.
__global__ __launch_bounds__(256) void transpose_conv(
    const float* __restrict__ Wq, const float* __restrict__ Wk,
    const float* __restrict__ Wv, const float* __restrict__ Wo,
    u16* __restrict__ wqt, u16* __restrict__ wkt,
    u16* __restrict__ wvt, u16* __restrict__ wot)
{
  int z = blockIdx.y;
  const float* src = (z == 0) ? Wq : (z == 1) ? Wk : (z == 2) ? Wv : Wo;
  u16* dst = (z == 0) ? wqt : (z == 1) ? wkt : (z == 2) ? wvt : wot;
  int C = (z < 3) ? 2048 : 256;   // src cols
  int R = (z < 3) ? 256 : 2048;   // src rows
  int TC = C >> 5;
  int tc = blockIdx.x % TC, tr = blockIdx.x / TC;
  __shared__ float tile[32][33];
  int j = threadIdx.x & 31, i0 = threadIdx.x >> 5;
#pragma unroll
  for (int p = 0; p < 4; p++)
    tile[i0 + p * 8][j] = src[(tr * 32 + i0 + p * 8) * C + tc * 32 + j];
  __syncthreads();
#pragma unroll
  for (int p = 0; p < 4; p++)
    dst[(tc * 32 + i0 + p * 8) * R + tr * 32 + j] = f2bf(tile[j][i0 + p * 8]);
}

// ---------------------------------------------------------------------------
// Kernel 2: LayerNorm for the 3 input streams, f32 -> bf16. One wave per row.
__global__ __launch_bounds__(256) void ln3_kernel(
    const float* __restrict__ xq, const float* __restrict__ xk, const float* __restrict__ xv,
    const float* __restrict__ gq, const float* __restrict__ bq,
    const float* __restrict__ gk, const float* __restrict__ bk,
    const float* __restrict__ gv, const float* __restrict__ bv,
    u16* __restrict__ oq, u16* __restrict__ ok, u16* __restrict__ ov)
{
  int z = blockIdx.y;
  const float* x = (z == 0) ? xq : (z == 1) ? xk : xv;
  const float* g = (z == 0) ? gq : (z == 1) ? gk : gv;
  const float* be = (z == 0) ? bq : (z == 1) ? bk : bv;
  u16* o = (z == 0) ? oq : (z == 1) ? ok : ov;
  int w = threadIdx.x >> 6, l = threadIdx.x & 63;
  int row = blockIdx.x * 4 + w;
  float4 x4 = *(const float4*)(x + row * 256 + l * 4);
  float s = x4.x + x4.y + x4.z + x4.w;
  float sq = x4.x * x4.x + x4.y * x4.y + x4.z * x4.z + x4.w * x4.w;
#pragma unroll
  for (int mm = 1; mm < 64; mm <<= 1) { s += __shfl_xor(s, mm); sq += __shfl_xor(sq, mm); }
  float mu = s * (1.f / 256.f);
  float var = sq * (1.f / 256.f) - mu * mu;
  float rs = rsqrtf(var + 1e-5f);
  float4 g4 = *(const float4*)(g + l * 4);
  float4 b4 = *(const float4*)(be + l * 4);
  ushort4 o4;
  o4.x = f2bf((x4.x - mu) * rs * g4.x + b4.x);
  o4.y = f2bf((x4.y - mu) * rs * g4.y + b4.y);
  o4.z = f2bf((x4.z - mu) * rs * g4.z + b4.z);
  o4.w = f2bf((x4.w - mu) * rs * g4.w + b4.w);
  *(ushort4*)(o + row * 256 + l * 4) = o4;
}

// ---------------------------------------------------------------------------
// Kernel 3: projection GEMM. C[8192][2048] = A[8192][256] * W[256][2048] (+bias)
// z==2 (V stream) writes V^T [32 bh][256 kd][2048 s] directly (fused transpose).
__global__ __launch_bounds__(256) void proj_gemm(
    const u16* __restrict__ qn, const u16* __restrict__ kn, const u16* __restrict__ vn,
    const u16* __restrict__ wqt, const u16* __restrict__ wkt, const u16* __restrict__ wvt,
    const float* __restrict__ bq, const float* __restrict__ bk, const float* __restrict__ bv,
    u16* __restrict__ qo, u16* __restrict__ ko, u16* __restrict__ vo)
{
  __shared__ u16 As[128 * 64];
  __shared__ u16 Bs[128 * 64];
  int z = blockIdx.z;
  const u16* A  = (z == 0) ? qn : (z == 1) ? kn : vn;
  const u16* Bt = (z == 0) ? wqt : (z == 1) ? wkt : wvt;
  const float* bias = (z == 0) ? bq : (z == 1) ? bk : bv;
  u16* Co = (z == 0) ? qo : (z == 1) ? ko : vo;
  float scale = (z == 0) ? 0.0625f : 1.0f;

  int i0 = blockIdx.x * 128, n0 = blockIdx.y * 128;
  int tid = threadIdx.x, w = tid >> 6, l = tid & 63;
  int wr = w >> 1, wc = w & 1, l15 = l & 15, qv = l >> 4;

  f32x4 acc[4][4] = {};

  for (int k0 = 0; k0 < 256; k0 += 64) {
    __syncthreads();
#pragma unroll
    for (int j = 0; j < 4; j++) {
      int c = (w * 4 + j) * 64 + l;
      int row = c >> 3, co = (c & 7) * 8;
      gload16(A + (i0 + row) * 256 + k0 + co, (char*)As + (w * 4 + j) * 1024);
      gload16(Bt + (n0 + row) * 256 + k0 + co, (char*)Bs + (w * 4 + j) * 1024);
    }
    __syncthreads();
#pragma unroll
    for (int kk = 0; kk < 2; kk++) {
      bf16x8 a[4], bfr[4];
#pragma unroll
      for (int m = 0; m < 4; m++)
        a[m] = *(const bf16x8*)(As + (wr * 64 + m * 16 + l15) * 64 + kk * 32 + qv * 8);
#pragma unroll
      for (int n = 0; n < 4; n++)
        bfr[n] = *(const bf16x8*)(Bs + (wc * 64 + n * 16 + l15) * 64 + kk * 32 + qv * 8);
#pragma unroll
      for (int m = 0; m < 4; m++)
#pragma unroll
        for (int n = 0; n < 4; n++) acc[m][n] = MFMA(a[m], bfr[n], acc[m][n]);
    }
  }

  if (z == 2) {
    // V^T epilogue: vt[(bb*8+h)*256 + kd][ss..ss+3], 8B packed stores.
#pragma unroll
    for (int n = 0; n < 4; n++) {
      int col = n0 + wc * 64 + n * 16 + l15;
      float bc = bias[col];
      int h = col >> 8, kd = col & 255;
#pragma unroll
      for (int m = 0; m < 4; m++) {
        int row0 = i0 + wr * 64 + m * 16 + qv * 4;
        int bb = row0 >> 11, ss = row0 & 2047;
        ushort4 o4;
        o4.x = f2bf(acc[m][n][0] + bc);
        o4.y = f2bf(acc[m][n][1] + bc);
        o4.z = f2bf(acc[m][n][2] + bc);
        o4.w = f2bf(acc[m][n][3] + bc);
        *(ushort4*)(Co + ((size_t)(bb * 8 + h) * 256 + kd) * 2048 + ss) = o4;
      }
    }
  } else {
#pragma unroll
    for (int n = 0; n < 4; n++) {
      int col = n0 + wc * 64 + n * 16 + l15;
      float bc = bias[col];
      int h = col >> 8, kd = col & 255;
#pragma unroll
      for (int m = 0; m < 4; m++) {
#pragma unroll
        for (int r = 0; r < 4; r++) {
          int row = i0 + wr * 64 + m * 16 + qv * 4 + r;
          int bb = row >> 11, ss = row & 2047;
          Co[((bb * 8 + h) * 2048 + ss) * 256 + kd] = f2bf((acc[m][n][r] + bc) * scale);
        }
      }
    }
  }
}

// ---------------------------------------------------------------------------
// Kernel 5: flash attention, 32x32x16 MFMA, swapped operands, double-buffered.
// Flat grid 256, XCD swizzle: bh = (f&7)|(((f>>3)&3)<<3) so the 8 q-tile
// blocks of one bh share an XCD L2 (per-bh K/V = 2 MB).
// LDS 128 KiB: two 64 KiB buffers, each [0,32K) K-tile + [32K,64K) V^T-tile.
__global__ __launch_bounds__(512, 2) void flash_attn(
    const u16* __restrict__ q, const u16* __restrict__ k,
    const u16* __restrict__ vt, u16* __restrict__ o)
{
  __shared__ char lds[131072];
  int f = blockIdx.x;
  int qt = f >> 5;
  int bh = (f & 7) | (((f >> 3) & 3) << 3);
  int b = bh >> 3, hh = bh & 7;
  int tid = threadIdx.x, w = tid >> 6, l = tid & 63;
  int l31 = l & 31, h = l >> 5;

  const u16* Q = q + (size_t)(bh * 2048 + qt * 256 + w * 32) * 256;
  const u16* K = k + (size_t)bh * 2048 * 256;
  const u16* V = vt + (size_t)bh * 256 * 2048;   // V^T [256][2048]

  // Q B-fragments: lane holds q-row = l31, d-slice = dt*16 + h*8 .. +8.
  bf16x8 qf[16];
#pragma unroll
  for (int dt = 0; dt < 16; dt++)
    qf[dt] = *(const bf16x8*)(Q + l31 * 256 + dt * 16 + h * 8);

  f32x16 oacc[8] = {};
  float m_ = -1e30f, lsum = 0.f;

  // Stage K/V tile t into base (swizzled; 8 waves x 8 gload16 = 64 KiB).
  auto stage = [&](int t, char* base) {
#pragma unroll
    for (int j = 0; j < 4; j++) {
      int c = w * 4 + j;
      int off = c * 1024 + l * 16;
      {
        int r = off >> 9, ps = l & 31;                 // K: row r, phys slot ps
        gload16(K + (size_t)(t * 64 + r) * 256 + ((ps ^ (r & 31)) << 3), base + off);
      }
      {
        int r = off >> 8, ps = l & 15;                 // V: 256B row r
        int lsl = ps ^ (r & 15);
        int d = r * 2 + (lsl >> 3);
        gload16(V + (size_t)d * 2048 + t * 64 + ((lsl & 7) << 3), base + 32768 + off);
      }
    }
  };

  stage(0, lds);
  __syncthreads();   // drains vmcnt(0) before barrier

  for (int t = 0; t < 32; t++) {
    char* cur = lds + (size_t)(t & 1) * 65536;
    char* nxt = lds + (size_t)((t + 1) & 1) * 65536;
    if (t + 1 < 32) stage(t + 1, nxt);   // prefetch next tile (DMA, in flight)

    // ---- QK^T: p0 = s-tile [0,32), p1 = s-tile [32,64); lane col q = l31.
    f32x16 p0 = {}, p1 = {};
    __builtin_amdgcn_s_setprio(1);
#pragma unroll
    for (int dt = 0; dt < 16; dt++) {
      int sl = ((dt * 2 + h) ^ l31) << 4;
      bf16x8 kf0 = *(const bf16x8*)(cur + l31 * 512 + sl);
      bf16x8 kf1 = *(const bf16x8*)(cur + (32 + l31) * 512 + sl);
      p0 = MFMA32(kf0, qf[dt], p0);
      p1 = MFMA32(kf1, qf[dt], p1);
    }
    __builtin_amdgcn_s_setprio(0);

    // ---- online softmax (lane-local; q = l31 on both halves).
    float n0 = fmaxf(fmaxf(p0[0], p0[1]), fmaxf(p0[2], p0[3]));
    float n1 = fmaxf(fmaxf(p0[4], p0[5]), fmaxf(p0[6], p0[7]));
    float n2 = fmaxf(fmaxf(p0[8], p0[9]), fmaxf(p0[10], p0[11]));
    float n3 = fmaxf(fmaxf(p0[12], p0[13]), fmaxf(p0[14], p0[15]));
    float n4 = fmaxf(fmaxf(p1[0], p1[1]), fmaxf(p1[2], p1[3]));
    float n5 = fmaxf(fmaxf(p1[4], p1[5]), fmaxf(p1[6], p1[7]));
    float n6 = fmaxf(fmaxf(p1[8], p1[9]), fmaxf(p1[10], p1[11]));
    float n7 = fmaxf(fmaxf(p1[12], p1[13]), fmaxf(p1[14], p1[15]));
    float mt = fmaxf(fmaxf(fmaxf(n0, n1), fmaxf(n2, n3)),
                     fmaxf(fmaxf(n4, n5), fmaxf(n6, n7)));
    mt = fmaxf(mt, __shfl_xor(mt, 32));
    if (__any(mt > m_ + 8.0f)) {               // defer-max (T13)
      float mn = fmaxf(m_, mt);
      float fsc = __expf(m_ - mn);
      lsum *= fsc;
#pragma unroll
      for (int dt = 0; dt < 8; dt++)
#pragma unroll
        for (int i = 0; i < 16; i++) oacc[dt][i] *= fsc;
      m_ = mn;
    }
#pragma unroll
    for (int i = 0; i < 16; i++) { p0[i] = __expf(p0[i] - m_); lsum += p0[i]; }
#pragma unroll
    for (int i = 0; i < 16; i++) { p1[i] = __expf(p1[i] - m_); lsum += p1[i]; }

    // ---- pack P to bf16 pairs (ascending s within each half).
    unsigned pw[16];
#pragma unroll
    for (int i = 0; i < 8; i++) pw[i] = pkbf(p0[2 * i], p0[2 * i + 1]);
#pragma unroll
    for (int i = 0; i < 8; i++) pw[8 + i] = pkbf(p1[2 * i], p1[2 * i + 1]);

    // ---- PV: per k-tile build P^T B-frag (cross-half exchange), 8 d-tiles.
#pragma unroll
    for (int kt = 0; kt < 4; kt++) {
      unsigned x0 = __shfl_xor(pw[4 * kt + 0], 32);
      unsigned x1 = __shfl_xor(pw[4 * kt + 1], 32);
      unsigned x2 = __shfl_xor(pw[4 * kt + 2], 32);
      unsigned x3 = __shfl_xor(pw[4 * kt + 3], 32);
      union { unsigned u[4]; bf16x8 v; } pa;
      pa.u[0] = h ? x2 : pw[4 * kt + 0];
      pa.u[1] = h ? x3 : pw[4 * kt + 1];
      pa.u[2] = h ? pw[4 * kt + 2] : x0;
      pa.u[3] = h ? pw[4 * kt + 3] : x1;
      __builtin_amdgcn_s_setprio(1);
#pragma unroll
      for (int dt = 0; dt < 8; dt++) {
        int d = dt * 32 + l31;
        int r = d >> 1;
        int lsl = (d & 1) * 8 + kt * 2 + h;
        bf16x8 vf = *(const bf16x8*)(cur + 32768 + r * 256 + ((lsl ^ (r & 15)) << 4));
        oacc[dt] = MFMA32(vf, pa.v, oacc[dt]);
      }
      __builtin_amdgcn_s_setprio(0);
    }

    asm volatile("s_waitcnt vmcnt(0)" ::: "memory");
    __syncthreads();
  }

  // ---- epilogue: normalize (lane-local q), transpose via LDS, store 16B.
  __syncthreads();
  float inv = 1.0f / (lsum + __shfl_xor(lsum, 32));
  char* wbase = (char*)lds + w * 8192;   // 16 q-rows x 512B per warp region
  int qr15 = l31 & 15;
#pragma unroll
  for (int ph = 0; ph < 2; ph++) {
    if ((l31 >> 4) == ph) {
#pragma unroll
      for (int dt = 0; dt < 8; dt++) {
#pragma unroll
        for (int rg = 0; rg < 4; rg++) {
          uint2 uu;
          uu.x = pkbf(oacc[dt][rg * 4 + 0] * inv, oacc[dt][rg * 4 + 1] * inv);
          uu.y = pkbf(oacc[dt][rg * 4 + 2] * inv, oacc[dt][rg * 4 + 3] * inv);
          *(uint2*)(wbase + qr15 * 512 + ((dt * 64 + rg * 16) ^ (qr15 << 4)) + h * 8) = uu;
        }
      }
    }
    asm volatile("s_waitcnt lgkmcnt(0)" ::: "memory");
    __builtin_amdgcn_sched_barrier(0);
#pragma unroll
    for (int c = 0; c < 8; c++) {
      int qr = c * 2 + h;
      uint4 vv = *(const uint4*)(wbase + qr * 512 + ((l31 ^ qr) << 4));
      int s = qt * 256 + w * 32 + ph * 16 + qr;
      *(uint4*)((char*)o + (size_t)(b * 2048 + s) * 4096 + hh * 512 + l31 * 16) = vv;
    }
    asm volatile("s_waitcnt lgkmcnt(0)" ::: "memory");
  }
}

// ---------------------------------------------------------------------------
// Kernel 6: output projection + bias + residual.
__global__ __launch_bounds__(256) void out_gemm(
    const u16* __restrict__ A, const u16* __restrict__ Bt,
    const float* __restrict__ bo, const float* __restrict__ resid,
    float* __restrict__ out)
{
  __shared__ u16 As[128 * 64];
  __shared__ u16 Bs[64 * 64];
  int i0 = blockIdx.x * 128, n0 = blockIdx.y * 64;
  int tid = threadIdx.x, w = tid >> 6, l = tid & 63, l15 = l & 15, qv = l >> 4;

  f32x4 acc[2][4] = {};

  for (int k0 = 0; k0 < 2048; k0 += 64) {
    __syncthreads();
#pragma unroll
    for (int j = 0; j < 4; j++) {
      int c = (w * 4 + j) * 64 + l;
      int row = c >> 3, co = (c & 7) * 8;
      gload16(A + (i0 + row) * 2048 + k0 + co, (char*)As + (w * 4 + j) * 1024);
    }
#pragma unroll
    for (int j = 0; j < 2; j++) {
      int c = (w * 2 + j) * 64 + l;
      int row = c >> 3, co = (c & 7) * 8;
      gload16(Bt + (n0 + row) * 2048 + k0 + co, (char*)Bs + (w * 2 + j) * 1024);
    }
    __syncthreads();
#pragma unroll
    for (int kk = 0; kk < 2; kk++) {
      bf16x8 a[2], bfr[4];
#pragma unroll
      for (int m = 0; m < 2; m++)
        a[m] = *(const bf16x8*)(As + (w * 32 + m * 16 + l15) * 64 + kk * 32 + qv * 8);
#pragma unroll
      for (int n = 0; n < 4; n++)
        bfr[n] = *(const bf16x8*)(Bs + (n * 16 + l15) * 64 + kk * 32 + qv * 8);
#pragma unroll
      for (int m = 0; m < 2; m++)
#pragma unroll
        for (int n = 0; n < 4; n++) acc[m][n] = MFMA(a[m], bfr[n], acc[m][n]);
    }
  }

#pragma unroll
  for (int n = 0; n < 4; n++) {
    int col = n0 + n * 16 + l15;
    float bc = bo[col];
#pragma unroll
    for (int m = 0; m < 2; m++)
#pragma unroll
      for (int r = 0; r < 4; r++) {
        int row = i0 + w * 32 + m * 16 + qv * 4 + r;
        out[row * 256 + col] = acc[m][n][r] + bc + resid[row * 256 + col];
      }
  }
}

// ---------------------------------------------------------------------------
extern "C" void kernel_launch(void* const* d_in, const int* in_sizes, int n_in,
                              void* d_out, int out_size, void* d_ws, size_t ws_size,
                              hipStream_t stream)
{
  const float* inq  = (const float*)d_in[0];
  const float* key  = (const float*)d_in[1];
  const float* val  = (const float*)d_in[2];
  const float* gq   = (const float*)d_in[3];
  const float* bqln = (const float*)d_in[4];
  const float* gk   = (const float*)d_in[5];
  const float* bkln = (const float*)d_in[6];
  const float* gv   = (const float*)d_in[7];
  const float* bvln = (const float*)d_in[8];
  const float* Wq   = (const float*)d_in[9];
  const float* bq   = (const float*)d_in[10];
  const float* Wk   = (const float*)d_in[11];
  const float* bk   = (const float*)d_in[12];
  const float* Wv   = (const float*)d_in[13];
  const float* bv   = (const float*)d_in[14];
  const float* Wo   = (const float*)d_in[15];
  const float* bo   = (const float*)d_in[16];

  char* ws = (char*)d_ws;
  const size_t MB = 1ull << 20;
  u16* wqt = (u16*)(ws + 0 * MB);    // [2048][256] bf16
  u16* wkt = (u16*)(ws + 1 * MB);
  u16* wvt = (u16*)(ws + 2 * MB);
  u16* wot = (u16*)(ws + 3 * MB);    // [256][2048] bf16
  u16* qn  = (u16*)(ws + 4 * MB);    // [8192][256] bf16
  u16* kn  = (u16*)(ws + 8 * MB);
  u16* vn  = (u16*)(ws + 12 * MB);
  u16* qws = (u16*)(ws + 16 * MB);   // [32][2048][256] bf16 (q, pre-scaled 1/16)
  u16* kws = (u16*)(ws + 48 * MB);   // [32][2048][256] bf16
  u16* attn = (u16*)(ws + 80 * MB);  // [8192][2048] bf16 (attention output)
  u16* vtw = (u16*)(ws + 112 * MB);  // [32][256][2048] bf16 (V^T, written by proj)

  transpose_conv<<<dim3(512, 4), 256, 0, stream>>>(Wq, Wk, Wv, Wo, wqt, wkt, wvt, wot);
  ln3_kernel<<<dim3(2048, 3), 256, 0, stream>>>(inq, key, val, gq, bqln, gk, bkln, gv, bvln,
                                                qn, kn, vn);
  proj_gemm<<<dim3(64, 16, 3), 256, 0, stream>>>(qn, kn, vn, wqt, wkt, wvt, bq, bk, bv,
                                                 qws, kws, vtw);
  flash_attn<<<256, 512, 0, stream>>>(qws, kws, vtw, attn);
  out_gemm<<<dim3(64, 4), 256, 0, stream>>>(attn, wot, bo, inq, (float*)d_out);
}